// Round 8
// baseline (565.195 us; speedup 1.0000x reference)
//
#include <hip/hip_runtime.h>
#include <stdint.h>
#include <math.h>

// ---------------------------------------------------------------------------
// Generator_44555990728950. B=4096 molecules, N=32 nodes (chain), H=128,
// 16 GAT layers. Two node classes per molecule (edge {0,31}, interior
// {1..30}); deterministic pipeline fp64; JAX partitionable threefry
// bit-exact; outputs fp32.
// R8: K-split wave pairs. Each molecule is handled by TWO waves, each doing
// half of every 128-k GEMV; partial sums combined through LDS per layer
// (f64 add commutative -> both waves get bit-identical full sums). Residual
// x kept in registers (identical in both waves); half-0 mirrors x to LDS for
// the broadcast k-loop read. 8192 waves total -> ~6 waves/SIMD residency.
// Tail phases split across the pair.
// ---------------------------------------------------------------------------

struct U2 { uint32_t a, b; };

// Threefry-2x32, 20 rounds, exactly as jax._src.prng
__device__ __forceinline__ U2 threefry(uint32_t k0, uint32_t k1, uint32_t x0, uint32_t x1) {
  const uint32_t ks2 = k0 ^ k1 ^ 0x1BD11BDAu;
#define TFR(r) { x0 += x1; x1 = (x1 << (r)) | (x1 >> (32 - (r))); x1 ^= x0; }
  x0 += k0;  x1 += k1;
  TFR(13) TFR(15) TFR(26) TFR(6)
  x0 += k1;  x1 += ks2 + 1u;
  TFR(17) TFR(29) TFR(16) TFR(24)
  x0 += ks2; x1 += k0 + 2u;
  TFR(13) TFR(15) TFR(26) TFR(6)
  x0 += k0;  x1 += k1 + 3u;
  TFR(17) TFR(29) TFR(16) TFR(24)
  x0 += k1;  x1 += ks2 + 4u;
  TFR(13) TFR(15) TFR(26) TFR(6)
  x0 += ks2; x1 += k0 + 5u;
#undef TFR
  U2 r; r.a = x0; r.b = x1; return r;
}

// partitionable random_bits, 32-bit: counter = flat index; fold o1^o2
__device__ __forceinline__ uint32_t pbits(uint32_t k0, uint32_t k1, uint32_t ctr) {
  U2 r = threefry(k0, k1, 0u, ctr);
  return r.a ^ r.b;
}

__device__ __forceinline__ float bits_to_unit(uint32_t bits) {
  return __uint_as_float((bits >> 9) | 0x3f800000u) - 1.0f;  // [0,1)
}

// f32 uniform(1e-6, 1-1e-6) -> gumbel, exactly jax's f32 path
__device__ __forceinline__ float jgumbel(uint32_t k0, uint32_t k1, uint32_t ctr) {
  const float minv = 1e-6f;
  const float maxv = (float)(1.0 - 1e-6);
  const float span = maxv - minv;
  float f = bits_to_unit(pbits(k0, k1, ctr));
  float u = fmaxf(minv, __fadd_rn(__fmul_rn(f, span), minv));
  return -logf(-logf(u));
}

extern "C" __global__ void __launch_bounds__(256, 6)
gen_kernel(const float* __restrict__ noise,
           const float* __restrict__ w1,
           const float* __restrict__ b1,
           const float* __restrict__ gat_w,
           const float* __restrict__ gat_b,
           const float* __restrict__ att_src,
           const float* __restrict__ att_dst,
           const float* __restrict__ w_atom,
           const float* __restrict__ b_atom,
           const float* __restrict__ w_hyb,
           const float* __restrict__ b_hyb,
           const float* __restrict__ w_deg,
           const float* __restrict__ b_deg,
           const float* __restrict__ w_chg,
           const float* __restrict__ b_chg,
           const float* __restrict__ w_arom,
           const float* __restrict__ b_arom,
           const float* __restrict__ w_eex,
           const float* __restrict__ b_eex,
           const float* __restrict__ w_ety,
           const float* __restrict__ b_ety,
           float* __restrict__ out)
{
  __shared__ __align__(16) double sX[2][128][2];      // {xe,xi} per k, 4 KB
  __shared__ __align__(16) double sPart[2][2][64][4]; // k-half partials, 16 KB
  __shared__ double sScr[2][32];                       // head logits
  __shared__ float  sNF[2][32][17];                    // node features
  __shared__ double sLP[2][64];                        // lp scratch

  const int t    = threadIdx.x;
  const int wv   = t >> 6;
  const int ms   = wv >> 1;        // molecule slot in block (0/1)
  const int half = wv & 1;         // k-half this wave owns
  const int ln   = t & 63;
  const int mol  = blockIdx.x * 2 + ms;
  const int c0   = ln << 1;        // lane's two columns

  double xe0, xi0, xe1, xi1;       // residual x in registers (both waves identical)

  // ---------------- phase 0: x0 = relu(noise @ w1 + b1) (full-k, redundant)
  {
    double* nz = &sPart[ms][0][0][0];          // 128-double scratch
    if (half == 0) {
      const float2 v = *(const float2*)(noise + (size_t)mol * 128 + c0);
      nz[c0] = (double)v.x; nz[c0 + 1] = (double)v.y;
    }
    __syncthreads();
    double h0 = 0.0, h1 = 0.0;
    #pragma unroll 8
    for (int k = 0; k < 128; ++k) {
      const double nx = nz[k];
      const float2 w  = *(const float2*)(w1 + k * 128 + c0);
      h0 = fma(nx, (double)w.x, h0);
      h1 = fma(nx, (double)w.y, h1);
    }
    const float2 bb = *(const float2*)(b1 + c0);
    xe0 = fmax(h0 + (double)bb.x, 0.0); xi0 = xe0;
    xe1 = fmax(h1 + (double)bb.y, 0.0); xi1 = xe1;
    if (half == 0) {
      double2 wa = {xe0, xi0}, wb = {xe1, xi1};
      *(double2*)&sX[ms][c0][0]     = wa;
      *(double2*)&sX[ms][c0 + 1][0] = wb;
    }
    __syncthreads();   // nz reads done + sX visible before layer loop
  }

  // ---------------- 16 GAT layers, K split across the wave pair
  for (int l = 0; l < 16; ++l) {
    const float* __restrict__ Wl = gat_w + (size_t)l * 16384 + (half << 6) * 128;
    double aEx = 0.0, aEy = 0.0, aIx = 0.0, aIy = 0.0;
    const int kbase = half << 6;
    #pragma unroll 8
    for (int kk = 0; kk < 64; ++kk) {
      const double2 X = *(const double2*)&sX[ms][kbase + kk][0];  // xe, xi
      const float2  w = *(const float2*)(Wl + kk * 128 + c0);
      const double wx = (double)w.x, wy = (double)w.y;
      aEx = fma(X.x, wx, aEx); aEy = fma(X.x, wy, aEy);
      aIx = fma(X.y, wx, aIx); aIy = fma(X.y, wy, aIy);
    }
    // exchange partials with sibling wave
    {
      double2 pa = {aEx, aEy}, pb = {aIx, aIy};
      *(double2*)&sPart[ms][half][ln][0] = pa;
      *(double2*)&sPart[ms][half][ln][2] = pb;
    }
    __syncthreads();
    {
      const double2 oa = *(const double2*)&sPart[ms][half ^ 1][ln][0];
      const double2 ob = *(const double2*)&sPart[ms][half ^ 1][ln][2];
      aEx += oa.x; aEy += oa.y; aIx += ob.x; aIy += ob.y;   // commutative: same bits both waves
    }
    {
      const float2 bb = *(const float2*)(gat_b + l * 128 + c0);
      aEx += (double)bb.x; aEy += (double)bb.y;
      aIx += (double)bb.x; aIy += (double)bb.y;
    }
    // attention scalars via wave butterfly (full 128-col sums now in-wave)
    const float2 av = *(const float2*)(att_src + l * 128 + c0);
    const float2 dv = *(const float2*)(att_dst + l * 128 + c0);
    const double ax = (double)av.x, ay = (double)av.y;
    const double dx = (double)dv.x, dy = (double)dv.y;
    double esE = fma(aEy, ay, aEx * ax), edE = fma(aEy, dy, aEx * dx);
    double esI = fma(aIy, ay, aIx * ax), edI = fma(aIy, dy, aIx * dx);
    #pragma unroll
    for (int o = 1; o < 64; o <<= 1) {
      esE += __shfl_xor(esE, o, 64); edE += __shfl_xor(edE, o, 64);
      esI += __shfl_xor(esI, o, 64); edI += __shfl_xor(edI, o, 64);
    }
    double s0 = edE + esE; s0 = (s0 >= 0.0) ? s0 : 0.2 * s0;
    double s1 = edE + esI; s1 = (s1 >= 0.0) ? s1 : 0.2 * s1;
    const double me  = fmax(s0, s1);
    const double p0  = exp(s0 - me), p1 = exp(s1 - me);
    const double den = p0 + p1;
    const double A0 = p0 / den, A1 = p1 / den;
    const double oEx = A0 * aEx + A1 * aIx;
    const double oEy = A0 * aEy + A1 * aIy;
    const double tIx = (1.0 / 3.0) * aIx, tIy = (1.0 / 3.0) * aIy;
    const double oIx = (tIx + tIx) + tIx;
    const double oIy = (tIy + tIy) + tIy;

    xe0 = fmax(xe0 + oEx, 0.0);  xi0 = fmax(xi0 + oIx, 0.0);
    xe1 = fmax(xe1 + oEy, 0.0);  xi1 = fmax(xi1 + oIy, 0.0);
    if (half == 0) {
      double2 na = {xe0, xi0}, nb = {xe1, xi1};
      *(double2*)&sX[ms][c0][0]     = na;
      *(double2*)&sX[ms][c0 + 1][0] = nb;
    }
    __syncthreads();
  }

  // ---------------- phase A: head logits per class, split across the pair
  if (half == 0) {
    if (ln < 10) {
      double ae = 0.0, aiv = 0.0;
      for (int c = 0; c < 128; ++c) {
        const double2 X = *(const double2*)&sX[ms][c][0];
        const double w_ = (double)w_atom[c * 10 + ln];
        ae  = fma(X.x, w_, ae);
        aiv = fma(X.y, w_, aiv);
      }
      const double ba = (double)b_atom[ln];
      sScr[ms][ln]      = ae + ba;
      sScr[ms][10 + ln] = aiv + ba;
    }
  } else {
    if (ln < 3) {
      double ae = 0.0, aiv = 0.0;
      for (int c = 0; c < 128; ++c) {
        const double2 X = *(const double2*)&sX[ms][c][0];
        const double w_ = (double)w_hyb[c * 3 + ln];
        ae  = fma(X.x, w_, ae);
        aiv = fma(X.y, w_, aiv);
      }
      const double bh = (double)b_hyb[ln];
      sScr[ms][20 + ln] = ae + bh;
      sScr[ms][23 + ln] = aiv + bh;
    } else if (ln < 6) {
      const int which = ln - 3;              // 0=deg 1=chg 2=arom
      const float* wp = (which == 0) ? w_deg : (which == 1) ? w_chg : w_arom;
      double ae = 0.0, aiv = 0.0;
      for (int c = 0; c < 128; ++c) {
        const double2 X = *(const double2*)&sX[ms][c][0];
        const double w_ = (double)wp[c];
        ae  = fma(X.x, w_, ae);
        aiv = fma(X.y, w_, aiv);
      }
      const double bz = (double)((which == 0) ? b_deg[0] : (which == 1) ? b_chg[0] : b_arom[0]);
      sScr[ms][26 + which] = ae + bz;
      sScr[ms][29 + which] = aiv + bz;
    }
  }
  __syncthreads();

  // partitionable split(key(42),4): child_i = threefry((0,42),(0,i))
  const U2 k0p = threefry(0u, 42u, 0u, 0u);
  const U2 k1p = threefry(0u, 42u, 0u, 1u);
  const U2 k2p = threefry(0u, 42u, 0u, 2u);
  const U2 k3p = threefry(0u, 42u, 0u, 3u);

  // ---------------- phase B: per-node sampling (half-0 wave, lanes 0..31)
  if (half == 0 && ln < 32) {
    const int n = ln;
    const int lb = (n == 0 || n == 31) ? 0 : 10;
    const int hb = (n == 0 || n == 31) ? 20 : 23;
    const int zb = (n == 0 || n == 31) ? 26 : 29;
    const double* scr = sScr[ms];

    double m = scr[lb];
    #pragma unroll
    for (int a = 1; a < 10; ++a) m = fmax(m, scr[lb + a]);
    double lsum = 0.0;
    #pragma unroll
    for (int a = 0; a < 10; ++a) lsum += exp(scr[lb + a] - m);
    const double lse = log(lsum);
    const uint32_t abase = ((uint32_t)mol * 32u + (uint32_t)n) * 10u;
    int asel = 0; double abest = 0.0;
    #pragma unroll
    for (int a = 0; a < 10; ++a) {
      const double g = (double)jgumbel(k0p.a, k0p.b, abase + (uint32_t)a);
      const double sc = scr[lb + a] + g;
      if (a == 0 || sc > abest) { abest = sc; asel = a; }
    }
    sLP[ms][n] = (scr[lb + asel] - m) - lse;

    double m2 = fmax(fmax(scr[hb], scr[hb + 1]), scr[hb + 2]);
    double ls2 = exp(scr[hb] - m2) + exp(scr[hb + 1] - m2) + exp(scr[hb + 2] - m2);
    const double lse2 = log(ls2);
    const uint32_t hbase = ((uint32_t)mol * 32u + (uint32_t)n) * 3u;
    int hsel = 0; double hbest = 0.0;
    #pragma unroll
    for (int j = 0; j < 3; ++j) {
      const double g = (double)jgumbel(k1p.a, k1p.b, hbase + (uint32_t)j);
      const double sc = scr[hb + j] + g;
      if (j == 0 || sc > hbest) { hbest = sc; hsel = j; }
    }
    sLP[ms][32 + n] = (scr[hb + hsel] - m2) - lse2;

    const double deg = 1.0 / (1.0 + exp(-scr[zb]));
    const double chg = tanh(scr[zb + 1]);
    const double pr  = 1.0 / (1.0 + exp(-scr[zb + 2]));
    const uint32_t ridx = (uint32_t)mol * 32u + (uint32_t)n;
    const double uu = (double)bits_to_unit(pbits(k2p.a, k2p.b, ridx));
    const double arom = (uu < pr) ? 1.0 : 0.0;
    const double valt[10] = {4.0/5.0, 3.0/5.0, 2.0/5.0, 1.0/5.0, 4.0/5.0,
                             2.0/5.0, 6.0/5.0, 1.0/5.0, 4.0/5.0, 4.0/5.0};
    double nf[17];
    #pragma unroll
    for (int i = 0; i < 10; ++i) nf[i] = (i == asel) ? 1.0 : 0.0;
    nf[10] = deg; nf[11] = chg;
    #pragma unroll
    for (int j = 0; j < 3; ++j) nf[12 + j] = (j == hsel) ? 1.0 : 0.0;
    nf[15] = arom; nf[16] = valt[asel];

    const size_t o = ((size_t)mol * 32 + n) * 17;
    #pragma unroll
    for (int i = 0; i < 17; ++i) {
      sNF[ms][n][i] = (float)nf[i];
      out[o + i] = (float)nf[i];
    }
  }
  __syncthreads();

  // ---------------- phase C: edges (half-1 wave) + lp means (half-0 wave)
  if (half == 0) {
    if (ln == 62) {
      double sa = 0.0;
      for (int n = 0; n < 32; ++n) sa += sLP[ms][n];
      out[2228224 + (size_t)mol] = (float)(sa / 32.0);
    } else if (ln == 63) {
      double sh = 0.0;
      for (int n = 0; n < 32; ++n) sh += sLP[ms][32 + n];
      out[2232320 + (size_t)mol] = (float)(sh / 32.0);
    }
  } else if (ln < 62) {
    const int e = ln;
    const int nu_ = (e < 31) ? e : (e - 30);
    const int nv_ = (e < 31) ? (e + 1) : (e - 31);
    double lex = 0.0;
    double lt[4] = {0.0, 0.0, 0.0, 0.0};
    for (int i = 0; i < 17; ++i) {
      const double f = (double)sNF[ms][nu_][i];
      lex = fma(f, (double)w_eex[i], lex);
      #pragma unroll
      for (int c = 0; c < 4; ++c) lt[c] = fma(f, (double)w_ety[i * 4 + c], lt[c]);
    }
    for (int i = 0; i < 17; ++i) {
      const double f = (double)sNF[ms][nv_][i];
      lex = fma(f, (double)w_eex[17 + i], lex);
      #pragma unroll
      for (int c = 0; c < 4; ++c) lt[c] = fma(f, (double)w_ety[(17 + i) * 4 + c], lt[c]);
    }
    lex += (double)b_eex[0];
    #pragma unroll
    for (int c = 0; c < 4; ++c) lt[c] += (double)b_ety[c];

    const double pex = 1.0 / (1.0 + exp(-lex));
    out[3252224 + (size_t)mol * 62 + e] = (pex > 0.5) ? 1.f : 0.f;

    const uint32_t tbase = ((uint32_t)mol * 62u + (uint32_t)e) * 4u;
    int tsel = 0; double tbest = 0.0;
    #pragma unroll
    for (int c = 0; c < 4; ++c) {
      const double g = (double)jgumbel(k3p.a, k3p.b, tbase + (uint32_t)c);
      const double sc = lt[c] + g;
      if (c == 0 || sc > tbest) { tbest = sc; tsel = c; }
    }
    const size_t o = 2236416 + ((size_t)mol * 62 + e) * 4;
    #pragma unroll
    for (int c = 0; c < 4; ++c) out[o + c] = (c == tsel) ? 1.f : 0.f;
  }
}

extern "C" void kernel_launch(void* const* d_in, const int* in_sizes, int n_in,
                              void* d_out, int out_size, void* d_ws, size_t ws_size,
                              hipStream_t stream) {
  (void)in_sizes; (void)n_in; (void)out_size; (void)d_ws; (void)ws_size;
  hipLaunchKernelGGL(gen_kernel, dim3(2048), dim3(256), 0, stream,
                     (const float*)d_in[0],  (const float*)d_in[1],
                     (const float*)d_in[2],  (const float*)d_in[3],
                     (const float*)d_in[4],  (const float*)d_in[5],
                     (const float*)d_in[6],  (const float*)d_in[7],
                     (const float*)d_in[8],  (const float*)d_in[9],
                     (const float*)d_in[10], (const float*)d_in[11],
                     (const float*)d_in[12], (const float*)d_in[13],
                     (const float*)d_in[14], (const float*)d_in[15],
                     (const float*)d_in[16], (const float*)d_in[17],
                     (const float*)d_in[18], (const float*)d_in[19],
                     (const float*)d_in[20], (float*)d_out);
}

// Round 9
// 450.925 us; speedup vs baseline: 1.2534x; 1.2534x over previous
//
#include <hip/hip_runtime.h>
#include <stdint.h>
#include <math.h>

// ---------------------------------------------------------------------------
// Generator_44555990728950. B=4096 molecules, N=32 nodes (chain), H=128,
// 16 GAT layers. Two node classes per molecule (edge {0,31}, interior
// {1..30}); deterministic pipeline fp64; JAX partitionable threefry
// bit-exact; outputs fp32.
// R9: R7 shape (1 mol/wave, 4 waves/block, wave-private x in LDS) +
//  (a) weights pre-converted to f64 in d_ws by a first kernel (no cvt in the
//      k-loop; loads feed FMA directly; f32->f64 exact => bit-identical),
//  (b) explicit depth-8 ping-pong software pipeline on W (global f64) and
//      x (LDS b128) so ~8 loads of each are in flight across FMA blocks.
// ---------------------------------------------------------------------------

struct U2 { uint32_t a, b; };

// Threefry-2x32, 20 rounds, exactly as jax._src.prng
__device__ __forceinline__ U2 threefry(uint32_t k0, uint32_t k1, uint32_t x0, uint32_t x1) {
  const uint32_t ks2 = k0 ^ k1 ^ 0x1BD11BDAu;
#define TFR(r) { x0 += x1; x1 = (x1 << (r)) | (x1 >> (32 - (r))); x1 ^= x0; }
  x0 += k0;  x1 += k1;
  TFR(13) TFR(15) TFR(26) TFR(6)
  x0 += k1;  x1 += ks2 + 1u;
  TFR(17) TFR(29) TFR(16) TFR(24)
  x0 += ks2; x1 += k0 + 2u;
  TFR(13) TFR(15) TFR(26) TFR(6)
  x0 += k0;  x1 += k1 + 3u;
  TFR(17) TFR(29) TFR(16) TFR(24)
  x0 += k1;  x1 += ks2 + 4u;
  TFR(13) TFR(15) TFR(26) TFR(6)
  x0 += ks2; x1 += k0 + 5u;
#undef TFR
  U2 r; r.a = x0; r.b = x1; return r;
}

// partitionable random_bits, 32-bit: counter = flat index; fold o1^o2
__device__ __forceinline__ uint32_t pbits(uint32_t k0, uint32_t k1, uint32_t ctr) {
  U2 r = threefry(k0, k1, 0u, ctr);
  return r.a ^ r.b;
}

__device__ __forceinline__ float bits_to_unit(uint32_t bits) {
  return __uint_as_float((bits >> 9) | 0x3f800000u) - 1.0f;  // [0,1)
}

// f32 uniform(1e-6, 1-1e-6) -> gumbel, exactly jax's f32 path
__device__ __forceinline__ float jgumbel(uint32_t k0, uint32_t k1, uint32_t ctr) {
  const float minv = 1e-6f;
  const float maxv = (float)(1.0 - 1e-6);
  const float span = maxv - minv;
  float f = bits_to_unit(pbits(k0, k1, ctr));
  float u = fmaxf(minv, __fadd_rn(__fmul_rn(f, span), minv));
  return -logf(-logf(u));
}

// ---------------- kernel 1: convert w1 + gat_w to f64 in workspace
extern "C" __global__ void __launch_bounds__(256)
cvt_kernel(const float* __restrict__ w1, const float* __restrict__ gat_w,
           double* __restrict__ wsd) {
  const int i = blockIdx.x * 256 + threadIdx.x;
  if (i < 16384)       wsd[i] = (double)w1[i];
  else if (i < 278528) wsd[i] = (double)gat_w[i - 16384];
}

#define NW 4   // waves per block; 1 molecule per wave

extern "C" __global__ void __launch_bounds__(256)
gen_kernel(const float* __restrict__ noise,
           const double* __restrict__ wsd,
           const float* __restrict__ b1,
           const float* __restrict__ gat_b,
           const float* __restrict__ att_src,
           const float* __restrict__ att_dst,
           const float* __restrict__ w_atom,
           const float* __restrict__ b_atom,
           const float* __restrict__ w_hyb,
           const float* __restrict__ b_hyb,
           const float* __restrict__ w_deg,
           const float* __restrict__ b_deg,
           const float* __restrict__ w_chg,
           const float* __restrict__ b_chg,
           const float* __restrict__ w_arom,
           const float* __restrict__ b_arom,
           const float* __restrict__ w_eex,
           const float* __restrict__ b_eex,
           const float* __restrict__ w_ety,
           const float* __restrict__ b_ety,
           float* __restrict__ out)
{
  __shared__ __align__(16) double sX[NW][128][2];      // {xe,xi} per k, 8 KB
  __shared__ double sScr[NW][32];
  __shared__ float  sNF[NW][32][17];
  __shared__ double sLP[NW][64];

  const int t  = threadIdx.x;
  const int wv = t >> 6;
  const int ln = t & 63;
  const int mol = blockIdx.x * NW + wv;
  const int c0 = ln << 1;                               // lane's two columns

  // ---------------- phase 0: x0 = relu(noise @ w1 + b1)
  {
    const float2 nz = *(const float2*)(noise + (size_t)mol * 128 + c0);
    sX[wv][c0][0]     = (double)nz.x;  sX[wv][c0][1]     = (double)nz.x;
    sX[wv][c0 + 1][0] = (double)nz.y;  sX[wv][c0 + 1][1] = (double)nz.y;
    double h0 = 0.0, h1 = 0.0;
    #pragma unroll 8
    for (int k = 0; k < 128; ++k) {
      const double nx = sX[wv][k][0];
      const double2 w = *(const double2*)(wsd + (size_t)k * 128 + c0);
      h0 = fma(nx, w.x, h0);
      h1 = fma(nx, w.y, h1);
    }
    const float2 bb = *(const float2*)(b1 + c0);
    const double x0a = fmax(h0 + (double)bb.x, 0.0);
    const double x0b = fmax(h1 + (double)bb.y, 0.0);
    double2 wa = {x0a, x0a}, wb = {x0b, x0b};
    *(double2*)&sX[wv][c0][0]     = wa;
    *(double2*)&sX[wv][c0 + 1][0] = wb;
  }

  // ---------------- 16 GAT layers, f64 W streamed with ping-pong pipeline
  for (int l = 0; l < 16; ++l) {
    __syncthreads();   // phase-keeper: 4 waves aligned for L1/L2 W reuse
    const double* __restrict__ Wl = wsd + 16384 + (size_t)l * 16384;
    double aEx = 0.0, aEy = 0.0, aIx = 0.0, aIy = 0.0;

    double2 wA[8], xA[8], wB[8], xB[8];
    #pragma unroll
    for (int i = 0; i < 8; ++i) {
      wA[i] = *(const double2*)(Wl + (size_t)i * 128 + c0);
      xA[i] = *(const double2*)&sX[wv][i][0];
    }
    for (int jb = 0; jb < 16; jb += 2) {
      {
        const int kb = (jb + 1) * 8;
        #pragma unroll
        for (int i = 0; i < 8; ++i) {
          wB[i] = *(const double2*)(Wl + (size_t)(kb + i) * 128 + c0);
          xB[i] = *(const double2*)&sX[wv][kb + i][0];
        }
      }
      #pragma unroll
      for (int i = 0; i < 8; ++i) {
        aEx = fma(xA[i].x, wA[i].x, aEx); aEy = fma(xA[i].x, wA[i].y, aEy);
        aIx = fma(xA[i].y, wA[i].x, aIx); aIy = fma(xA[i].y, wA[i].y, aIy);
      }
      if (jb + 2 < 16) {
        const int kb = (jb + 2) * 8;
        #pragma unroll
        for (int i = 0; i < 8; ++i) {
          wA[i] = *(const double2*)(Wl + (size_t)(kb + i) * 128 + c0);
          xA[i] = *(const double2*)&sX[wv][kb + i][0];
        }
      }
      #pragma unroll
      for (int i = 0; i < 8; ++i) {
        aEx = fma(xB[i].x, wB[i].x, aEx); aEy = fma(xB[i].x, wB[i].y, aEy);
        aIx = fma(xB[i].y, wB[i].x, aIx); aIy = fma(xB[i].y, wB[i].y, aIy);
      }
    }

    {
      const float2 bb = *(const float2*)(gat_b + l * 128 + c0);
      aEx += (double)bb.x; aEy += (double)bb.y;
      aIx += (double)bb.x; aIy += (double)bb.y;
    }
    // attention scalars via wave butterfly
    const float2 av = *(const float2*)(att_src + l * 128 + c0);
    const float2 dv = *(const float2*)(att_dst + l * 128 + c0);
    const double ax = (double)av.x, ay = (double)av.y;
    const double dx = (double)dv.x, dy = (double)dv.y;
    double esE = fma(aEy, ay, aEx * ax), edE = fma(aEy, dy, aEx * dx);
    double esI = fma(aIy, ay, aIx * ax), edI = fma(aIy, dy, aIx * dx);
    #pragma unroll
    for (int o = 1; o < 64; o <<= 1) {
      esE += __shfl_xor(esE, o, 64); edE += __shfl_xor(edE, o, 64);
      esI += __shfl_xor(esI, o, 64); edI += __shfl_xor(edI, o, 64);
    }
    const double2 ra = *(const double2*)&sX[wv][c0][0];
    const double2 rb = *(const double2*)&sX[wv][c0 + 1][0];

    double s0 = edE + esE; s0 = (s0 >= 0.0) ? s0 : 0.2 * s0;
    double s1 = edE + esI; s1 = (s1 >= 0.0) ? s1 : 0.2 * s1;
    const double me  = fmax(s0, s1);
    const double p0  = exp(s0 - me), p1 = exp(s1 - me);
    const double den = p0 + p1;
    const double A0 = p0 / den, A1 = p1 / den;
    const double oEx = A0 * aEx + A1 * aIx;
    const double oEy = A0 * aEy + A1 * aIy;
    const double tIx = (1.0 / 3.0) * aIx, tIy = (1.0 / 3.0) * aIy;
    const double oIx = (tIx + tIx) + tIx;
    const double oIy = (tIy + tIy) + tIy;

    double2 na, nb;
    na.x = fmax(ra.x + oEx, 0.0);  na.y = fmax(ra.y + oIx, 0.0);
    nb.x = fmax(rb.x + oEy, 0.0);  nb.y = fmax(rb.y + oIy, 0.0);
    *(double2*)&sX[wv][c0][0]     = na;
    *(double2*)&sX[wv][c0 + 1][0] = nb;
  }

  // ---------------- phase A: head logits per class (lanes 0..15)
  if (ln < 16) {
    double ae = 0.0, aiv = 0.0;
    if (ln < 10) {
      for (int c = 0; c < 128; ++c) {
        const double2 X = *(const double2*)&sX[wv][c][0];
        const double wv_ = (double)w_atom[c * 10 + ln];
        ae  = fma(X.x, wv_, ae);
        aiv = fma(X.y, wv_, aiv);
      }
      const double ba = (double)b_atom[ln];
      sScr[wv][ln]      = ae + ba;
      sScr[wv][10 + ln] = aiv + ba;
    } else if (ln < 13) {
      const int j = ln - 10;
      for (int c = 0; c < 128; ++c) {
        const double2 X = *(const double2*)&sX[wv][c][0];
        const double wv_ = (double)w_hyb[c * 3 + j];
        ae  = fma(X.x, wv_, ae);
        aiv = fma(X.y, wv_, aiv);
      }
      const double bh = (double)b_hyb[j];
      sScr[wv][20 + j] = ae + bh;
      sScr[wv][23 + j] = aiv + bh;
    } else {
      const int which = ln - 13;             // 0=deg 1=chg 2=arom
      const float* wp = (which == 0) ? w_deg : (which == 1) ? w_chg : w_arom;
      for (int c = 0; c < 128; ++c) {
        const double2 X = *(const double2*)&sX[wv][c][0];
        const double wv_ = (double)wp[c];
        ae  = fma(X.x, wv_, ae);
        aiv = fma(X.y, wv_, aiv);
      }
      const double bz = (double)((which == 0) ? b_deg[0] : (which == 1) ? b_chg[0] : b_arom[0]);
      sScr[wv][26 + which] = ae + bz;
      sScr[wv][29 + which] = aiv + bz;
    }
  }

  // partitionable split(key(42),4): child_i = threefry((0,42),(0,i))
  const U2 k0p = threefry(0u, 42u, 0u, 0u);
  const U2 k1p = threefry(0u, 42u, 0u, 1u);
  const U2 k2p = threefry(0u, 42u, 0u, 2u);
  const U2 k3p = threefry(0u, 42u, 0u, 3u);

  // ---------------- phase B: per-node sampling (lanes 0..31)
  if (ln < 32) {
    const int n = ln;
    const int lb = (n == 0 || n == 31) ? 0 : 10;
    const int hb = (n == 0 || n == 31) ? 20 : 23;
    const int zb = (n == 0 || n == 31) ? 26 : 29;
    const double* scr = sScr[wv];

    double m = scr[lb];
    #pragma unroll
    for (int a = 1; a < 10; ++a) m = fmax(m, scr[lb + a]);
    double lsum = 0.0;
    #pragma unroll
    for (int a = 0; a < 10; ++a) lsum += exp(scr[lb + a] - m);
    const double lse = log(lsum);
    const uint32_t abase = ((uint32_t)mol * 32u + (uint32_t)n) * 10u;
    int asel = 0; double abest = 0.0;
    #pragma unroll
    for (int a = 0; a < 10; ++a) {
      const double g = (double)jgumbel(k0p.a, k0p.b, abase + (uint32_t)a);
      const double sc = scr[lb + a] + g;
      if (a == 0 || sc > abest) { abest = sc; asel = a; }
    }
    sLP[wv][n] = (scr[lb + asel] - m) - lse;

    double m2 = fmax(fmax(scr[hb], scr[hb + 1]), scr[hb + 2]);
    double ls2 = exp(scr[hb] - m2) + exp(scr[hb + 1] - m2) + exp(scr[hb + 2] - m2);
    const double lse2 = log(ls2);
    const uint32_t hbase = ((uint32_t)mol * 32u + (uint32_t)n) * 3u;
    int hsel = 0; double hbest = 0.0;
    #pragma unroll
    for (int j = 0; j < 3; ++j) {
      const double g = (double)jgumbel(k1p.a, k1p.b, hbase + (uint32_t)j);
      const double sc = scr[hb + j] + g;
      if (j == 0 || sc > hbest) { hbest = sc; hsel = j; }
    }
    sLP[wv][32 + n] = (scr[hb + hsel] - m2) - lse2;

    const double deg = 1.0 / (1.0 + exp(-scr[zb]));
    const double chg = tanh(scr[zb + 1]);
    const double pr  = 1.0 / (1.0 + exp(-scr[zb + 2]));
    const uint32_t ridx = (uint32_t)mol * 32u + (uint32_t)n;
    const double uu = (double)bits_to_unit(pbits(k2p.a, k2p.b, ridx));
    const double arom = (uu < pr) ? 1.0 : 0.0;
    const double valt[10] = {4.0/5.0, 3.0/5.0, 2.0/5.0, 1.0/5.0, 4.0/5.0,
                             2.0/5.0, 6.0/5.0, 1.0/5.0, 4.0/5.0, 4.0/5.0};
    double nf[17];
    #pragma unroll
    for (int i = 0; i < 10; ++i) nf[i] = (i == asel) ? 1.0 : 0.0;
    nf[10] = deg; nf[11] = chg;
    #pragma unroll
    for (int j = 0; j < 3; ++j) nf[12 + j] = (j == hsel) ? 1.0 : 0.0;
    nf[15] = arom; nf[16] = valt[asel];

    const size_t o = ((size_t)mol * 32 + n) * 17;
    #pragma unroll
    for (int i = 0; i < 17; ++i) {
      sNF[wv][n][i] = (float)nf[i];
      out[o + i] = (float)nf[i];
    }
  }

  // ---------------- phase C: lp means + edge heads
  if (ln == 62) {
    double sa = 0.0;
    for (int n = 0; n < 32; ++n) sa += sLP[wv][n];
    out[2228224 + (size_t)mol] = (float)(sa / 32.0);
  } else if (ln == 63) {
    double sh = 0.0;
    for (int n = 0; n < 32; ++n) sh += sLP[wv][32 + n];
    out[2232320 + (size_t)mol] = (float)(sh / 32.0);
  } else {
    const int e = ln;                       // 0..61
    const int nu_ = (e < 31) ? e : (e - 30);
    const int nv_ = (e < 31) ? (e + 1) : (e - 31);
    double lex = 0.0;
    double lt[4] = {0.0, 0.0, 0.0, 0.0};
    for (int i = 0; i < 17; ++i) {
      const double f = (double)sNF[wv][nu_][i];
      lex = fma(f, (double)w_eex[i], lex);
      #pragma unroll
      for (int c = 0; c < 4; ++c) lt[c] = fma(f, (double)w_ety[i * 4 + c], lt[c]);
    }
    for (int i = 0; i < 17; ++i) {
      const double f = (double)sNF[wv][nv_][i];
      lex = fma(f, (double)w_eex[17 + i], lex);
      #pragma unroll
      for (int c = 0; c < 4; ++c) lt[c] = fma(f, (double)w_ety[(17 + i) * 4 + c], lt[c]);
    }
    lex += (double)b_eex[0];
    #pragma unroll
    for (int c = 0; c < 4; ++c) lt[c] += (double)b_ety[c];

    const double pex = 1.0 / (1.0 + exp(-lex));
    out[3252224 + (size_t)mol * 62 + e] = (pex > 0.5) ? 1.f : 0.f;

    const uint32_t tbase = ((uint32_t)mol * 62u + (uint32_t)e) * 4u;
    int tsel = 0; double tbest = 0.0;
    #pragma unroll
    for (int c = 0; c < 4; ++c) {
      const double g = (double)jgumbel(k3p.a, k3p.b, tbase + (uint32_t)c);
      const double sc = lt[c] + g;
      if (c == 0 || sc > tbest) { tbest = sc; tsel = c; }
    }
    const size_t o = 2236416 + ((size_t)mol * 62 + e) * 4;
    #pragma unroll
    for (int c = 0; c < 4; ++c) out[o + c] = (c == tsel) ? 1.f : 0.f;
  }
}

extern "C" void kernel_launch(void* const* d_in, const int* in_sizes, int n_in,
                              void* d_out, int out_size, void* d_ws, size_t ws_size,
                              hipStream_t stream) {
  (void)in_sizes; (void)n_in; (void)out_size; (void)ws_size;
  double* wsd = (double*)d_ws;
  hipLaunchKernelGGL(cvt_kernel, dim3(1088), dim3(256), 0, stream,
                     (const float*)d_in[1], (const float*)d_in[3], wsd);
  hipLaunchKernelGGL(gen_kernel, dim3(1024), dim3(256), 0, stream,
                     (const float*)d_in[0],  (const double*)wsd,
                     (const float*)d_in[2],  (const float*)d_in[4],
                     (const float*)d_in[5],  (const float*)d_in[6],
                     (const float*)d_in[7],  (const float*)d_in[8],
                     (const float*)d_in[9],  (const float*)d_in[10],
                     (const float*)d_in[11], (const float*)d_in[12],
                     (const float*)d_in[13], (const float*)d_in[14],
                     (const float*)d_in[15], (const float*)d_in[16],
                     (const float*)d_in[17], (const float*)d_in[18],
                     (const float*)d_in[19], (const float*)d_in[20],
                     (float*)d_out);
}

// Round 10
// 432.323 us; speedup vs baseline: 1.3073x; 1.0430x over previous
//
#include <hip/hip_runtime.h>
#include <stdint.h>
#include <math.h>

// ---------------------------------------------------------------------------
// Generator_44555990728950. B=4096 molecules, N=32 nodes (chain), H=128,
// 16 GAT layers. Two node classes per molecule (edge {0,31}, interior
// {1..30}); deterministic pipeline fp64; JAX partitionable threefry
// bit-exact; outputs fp32.
// R10: R8's K-split wave pairs (2 waves per molecule, each half of every
// 128-k GEMV; partials combined via LDS -> bit-identical full sums) WITHOUT
// the launch-bounds VGPR cap that crippled R8 (VGPR 32 -> no load lookahead).
// Natural regalloc (~52 VGPR) keeps unroll-8 pipelining AND still fits
// 8 waves/SIMD (LDS 18KB -> 8 blocks/CU). 8192 waves total.
// ---------------------------------------------------------------------------

struct U2 { uint32_t a, b; };

// Threefry-2x32, 20 rounds, exactly as jax._src.prng
__device__ __forceinline__ U2 threefry(uint32_t k0, uint32_t k1, uint32_t x0, uint32_t x1) {
  const uint32_t ks2 = k0 ^ k1 ^ 0x1BD11BDAu;
#define TFR(r) { x0 += x1; x1 = (x1 << (r)) | (x1 >> (32 - (r))); x1 ^= x0; }
  x0 += k0;  x1 += k1;
  TFR(13) TFR(15) TFR(26) TFR(6)
  x0 += k1;  x1 += ks2 + 1u;
  TFR(17) TFR(29) TFR(16) TFR(24)
  x0 += ks2; x1 += k0 + 2u;
  TFR(13) TFR(15) TFR(26) TFR(6)
  x0 += k0;  x1 += k1 + 3u;
  TFR(17) TFR(29) TFR(16) TFR(24)
  x0 += k1;  x1 += ks2 + 4u;
  TFR(13) TFR(15) TFR(26) TFR(6)
  x0 += ks2; x1 += k0 + 5u;
#undef TFR
  U2 r; r.a = x0; r.b = x1; return r;
}

// partitionable random_bits, 32-bit: counter = flat index; fold o1^o2
__device__ __forceinline__ uint32_t pbits(uint32_t k0, uint32_t k1, uint32_t ctr) {
  U2 r = threefry(k0, k1, 0u, ctr);
  return r.a ^ r.b;
}

__device__ __forceinline__ float bits_to_unit(uint32_t bits) {
  return __uint_as_float((bits >> 9) | 0x3f800000u) - 1.0f;  // [0,1)
}

// f32 uniform(1e-6, 1-1e-6) -> gumbel, exactly jax's f32 path
__device__ __forceinline__ float jgumbel(uint32_t k0, uint32_t k1, uint32_t ctr) {
  const float minv = 1e-6f;
  const float maxv = (float)(1.0 - 1e-6);
  const float span = maxv - minv;
  float f = bits_to_unit(pbits(k0, k1, ctr));
  float u = fmaxf(minv, __fadd_rn(__fmul_rn(f, span), minv));
  return -logf(-logf(u));
}

extern "C" __global__ void __launch_bounds__(256)
gen_kernel(const float* __restrict__ noise,
           const float* __restrict__ w1,
           const float* __restrict__ b1,
           const float* __restrict__ gat_w,
           const float* __restrict__ gat_b,
           const float* __restrict__ att_src,
           const float* __restrict__ att_dst,
           const float* __restrict__ w_atom,
           const float* __restrict__ b_atom,
           const float* __restrict__ w_hyb,
           const float* __restrict__ b_hyb,
           const float* __restrict__ w_deg,
           const float* __restrict__ b_deg,
           const float* __restrict__ w_chg,
           const float* __restrict__ b_chg,
           const float* __restrict__ w_arom,
           const float* __restrict__ b_arom,
           const float* __restrict__ w_eex,
           const float* __restrict__ b_eex,
           const float* __restrict__ w_ety,
           const float* __restrict__ b_ety,
           float* __restrict__ out)
{
  __shared__ __align__(16) double sX[2][128][2];      // {xe,xi} per k, 4 KB
  __shared__ __align__(16) double sPart[2][2][64][4]; // k-half partials, 16 KB
  __shared__ double sScr[2][32];                       // head logits
  __shared__ float  sNF[2][32][17];                    // node features
  __shared__ double sLP[2][64];                        // lp scratch

  const int t    = threadIdx.x;
  const int wv   = t >> 6;
  const int ms   = wv >> 1;        // molecule slot in block (0/1)
  const int half = wv & 1;         // k-half this wave owns
  const int ln   = t & 63;
  const int mol  = blockIdx.x * 2 + ms;
  const int c0   = ln << 1;        // lane's two columns

  double xe0, xi0, xe1, xi1;       // residual x in registers (both waves identical)

  // ---------------- phase 0: x0 = relu(noise @ w1 + b1) (full-k, redundant)
  {
    double* nz = &sPart[ms][0][0][0];          // 128-double scratch
    if (half == 0) {
      const float2 v = *(const float2*)(noise + (size_t)mol * 128 + c0);
      nz[c0] = (double)v.x; nz[c0 + 1] = (double)v.y;
    }
    __syncthreads();
    double h0 = 0.0, h1 = 0.0;
    #pragma unroll 8
    for (int k = 0; k < 128; ++k) {
      const double nx = nz[k];
      const float2 w  = *(const float2*)(w1 + k * 128 + c0);
      h0 = fma(nx, (double)w.x, h0);
      h1 = fma(nx, (double)w.y, h1);
    }
    const float2 bb = *(const float2*)(b1 + c0);
    xe0 = fmax(h0 + (double)bb.x, 0.0); xi0 = xe0;
    xe1 = fmax(h1 + (double)bb.y, 0.0); xi1 = xe1;
    __syncthreads();   // everyone done reading nz before sX (aliased region) is written
    if (half == 0) {
      double2 wa = {xe0, xi0}, wb = {xe1, xi1};
      *(double2*)&sX[ms][c0][0]     = wa;
      *(double2*)&sX[ms][c0 + 1][0] = wb;
    }
    __syncthreads();   // sX visible before layer loop
  }

  // ---------------- 16 GAT layers, K split across the wave pair
  for (int l = 0; l < 16; ++l) {
    const float* __restrict__ Wl = gat_w + (size_t)l * 16384 + (half << 6) * 128;
    double aEx = 0.0, aEy = 0.0, aIx = 0.0, aIy = 0.0;
    const int kbase = half << 6;
    #pragma unroll 8
    for (int kk = 0; kk < 64; ++kk) {
      const double2 X = *(const double2*)&sX[ms][kbase + kk][0];  // xe, xi
      const float2  w = *(const float2*)(Wl + kk * 128 + c0);
      const double wx = (double)w.x, wy = (double)w.y;
      aEx = fma(X.x, wx, aEx); aEy = fma(X.x, wy, aEy);
      aIx = fma(X.y, wx, aIx); aIy = fma(X.y, wy, aIy);
    }
    // exchange partials with sibling wave
    {
      double2 pa = {aEx, aEy}, pb = {aIx, aIy};
      *(double2*)&sPart[ms][half][ln][0] = pa;
      *(double2*)&sPart[ms][half][ln][2] = pb;
    }
    __syncthreads();
    {
      const double2 oa = *(const double2*)&sPart[ms][half ^ 1][ln][0];
      const double2 ob = *(const double2*)&sPart[ms][half ^ 1][ln][2];
      aEx += oa.x; aEy += oa.y; aIx += ob.x; aIy += ob.y;   // commutative: same bits both waves
    }
    {
      const float2 bb = *(const float2*)(gat_b + l * 128 + c0);
      aEx += (double)bb.x; aEy += (double)bb.y;
      aIx += (double)bb.x; aIy += (double)bb.y;
    }
    // attention scalars via wave butterfly (full 128-col sums now in-wave)
    const float2 av = *(const float2*)(att_src + l * 128 + c0);
    const float2 dv = *(const float2*)(att_dst + l * 128 + c0);
    const double ax = (double)av.x, ay = (double)av.y;
    const double dx = (double)dv.x, dy = (double)dv.y;
    double esE = fma(aEy, ay, aEx * ax), edE = fma(aEy, dy, aEx * dx);
    double esI = fma(aIy, ay, aIx * ax), edI = fma(aIy, dy, aIx * dx);
    #pragma unroll
    for (int o = 1; o < 64; o <<= 1) {
      esE += __shfl_xor(esE, o, 64); edE += __shfl_xor(edE, o, 64);
      esI += __shfl_xor(esI, o, 64); edI += __shfl_xor(edI, o, 64);
    }
    double s0 = edE + esE; s0 = (s0 >= 0.0) ? s0 : 0.2 * s0;
    double s1 = edE + esI; s1 = (s1 >= 0.0) ? s1 : 0.2 * s1;
    const double me  = fmax(s0, s1);
    const double p0  = exp(s0 - me), p1 = exp(s1 - me);
    const double den = p0 + p1;
    const double A0 = p0 / den, A1 = p1 / den;
    const double oEx = A0 * aEx + A1 * aIx;
    const double oEy = A0 * aEy + A1 * aIy;
    const double tIx = (1.0 / 3.0) * aIx, tIy = (1.0 / 3.0) * aIy;
    const double oIx = (tIx + tIx) + tIx;
    const double oIy = (tIy + tIy) + tIy;

    xe0 = fmax(xe0 + oEx, 0.0);  xi0 = fmax(xi0 + oIx, 0.0);
    xe1 = fmax(xe1 + oEy, 0.0);  xi1 = fmax(xi1 + oIy, 0.0);
    if (half == 0) {
      double2 na = {xe0, xi0}, nb = {xe1, xi1};
      *(double2*)&sX[ms][c0][0]     = na;
      *(double2*)&sX[ms][c0 + 1][0] = nb;
    }
    __syncthreads();
  }

  // ---------------- phase A: head logits per class, split across the pair
  if (half == 0) {
    if (ln < 10) {
      double ae = 0.0, aiv = 0.0;
      for (int c = 0; c < 128; ++c) {
        const double2 X = *(const double2*)&sX[ms][c][0];
        const double w_ = (double)w_atom[c * 10 + ln];
        ae  = fma(X.x, w_, ae);
        aiv = fma(X.y, w_, aiv);
      }
      const double ba = (double)b_atom[ln];
      sScr[ms][ln]      = ae + ba;
      sScr[ms][10 + ln] = aiv + ba;
    }
  } else {
    if (ln < 3) {
      double ae = 0.0, aiv = 0.0;
      for (int c = 0; c < 128; ++c) {
        const double2 X = *(const double2*)&sX[ms][c][0];
        const double w_ = (double)w_hyb[c * 3 + ln];
        ae  = fma(X.x, w_, ae);
        aiv = fma(X.y, w_, aiv);
      }
      const double bh = (double)b_hyb[ln];
      sScr[ms][20 + ln] = ae + bh;
      sScr[ms][23 + ln] = aiv + bh;
    } else if (ln < 6) {
      const int which = ln - 3;              // 0=deg 1=chg 2=arom
      const float* wp = (which == 0) ? w_deg : (which == 1) ? w_chg : w_arom;
      double ae = 0.0, aiv = 0.0;
      for (int c = 0; c < 128; ++c) {
        const double2 X = *(const double2*)&sX[ms][c][0];
        const double w_ = (double)wp[c];
        ae  = fma(X.x, w_, ae);
        aiv = fma(X.y, w_, aiv);
      }
      const double bz = (double)((which == 0) ? b_deg[0] : (which == 1) ? b_chg[0] : b_arom[0]);
      sScr[ms][26 + which] = ae + bz;
      sScr[ms][29 + which] = aiv + bz;
    }
  }
  __syncthreads();

  // partitionable split(key(42),4): child_i = threefry((0,42),(0,i))
  const U2 k0p = threefry(0u, 42u, 0u, 0u);
  const U2 k1p = threefry(0u, 42u, 0u, 1u);
  const U2 k2p = threefry(0u, 42u, 0u, 2u);
  const U2 k3p = threefry(0u, 42u, 0u, 3u);

  // ---------------- phase B: per-node sampling (half-0 wave, lanes 0..31)
  if (half == 0 && ln < 32) {
    const int n = ln;
    const int lb = (n == 0 || n == 31) ? 0 : 10;
    const int hb = (n == 0 || n == 31) ? 20 : 23;
    const int zb = (n == 0 || n == 31) ? 26 : 29;
    const double* scr = sScr[ms];

    double m = scr[lb];
    #pragma unroll
    for (int a = 1; a < 10; ++a) m = fmax(m, scr[lb + a]);
    double lsum = 0.0;
    #pragma unroll
    for (int a = 0; a < 10; ++a) lsum += exp(scr[lb + a] - m);
    const double lse = log(lsum);
    const uint32_t abase = ((uint32_t)mol * 32u + (uint32_t)n) * 10u;
    int asel = 0; double abest = 0.0;
    #pragma unroll
    for (int a = 0; a < 10; ++a) {
      const double g = (double)jgumbel(k0p.a, k0p.b, abase + (uint32_t)a);
      const double sc = scr[lb + a] + g;
      if (a == 0 || sc > abest) { abest = sc; asel = a; }
    }
    sLP[ms][n] = (scr[lb + asel] - m) - lse;

    double m2 = fmax(fmax(scr[hb], scr[hb + 1]), scr[hb + 2]);
    double ls2 = exp(scr[hb] - m2) + exp(scr[hb + 1] - m2) + exp(scr[hb + 2] - m2);
    const double lse2 = log(ls2);
    const uint32_t hbase = ((uint32_t)mol * 32u + (uint32_t)n) * 3u;
    int hsel = 0; double hbest = 0.0;
    #pragma unroll
    for (int j = 0; j < 3; ++j) {
      const double g = (double)jgumbel(k1p.a, k1p.b, hbase + (uint32_t)j);
      const double sc = scr[hb + j] + g;
      if (j == 0 || sc > hbest) { hbest = sc; hsel = j; }
    }
    sLP[ms][32 + n] = (scr[hb + hsel] - m2) - lse2;

    const double deg = 1.0 / (1.0 + exp(-scr[zb]));
    const double chg = tanh(scr[zb + 1]);
    const double pr  = 1.0 / (1.0 + exp(-scr[zb + 2]));
    const uint32_t ridx = (uint32_t)mol * 32u + (uint32_t)n;
    const double uu = (double)bits_to_unit(pbits(k2p.a, k2p.b, ridx));
    const double arom = (uu < pr) ? 1.0 : 0.0;
    const double valt[10] = {4.0/5.0, 3.0/5.0, 2.0/5.0, 1.0/5.0, 4.0/5.0,
                             2.0/5.0, 6.0/5.0, 1.0/5.0, 4.0/5.0, 4.0/5.0};
    double nf[17];
    #pragma unroll
    for (int i = 0; i < 10; ++i) nf[i] = (i == asel) ? 1.0 : 0.0;
    nf[10] = deg; nf[11] = chg;
    #pragma unroll
    for (int j = 0; j < 3; ++j) nf[12 + j] = (j == hsel) ? 1.0 : 0.0;
    nf[15] = arom; nf[16] = valt[asel];

    const size_t o = ((size_t)mol * 32 + n) * 17;
    #pragma unroll
    for (int i = 0; i < 17; ++i) {
      sNF[ms][n][i] = (float)nf[i];
      out[o + i] = (float)nf[i];
    }
  }
  __syncthreads();

  // ---------------- phase C: edges (half-1 wave) + lp means (half-0 wave)
  if (half == 0) {
    if (ln == 62) {
      double sa = 0.0;
      for (int n = 0; n < 32; ++n) sa += sLP[ms][n];
      out[2228224 + (size_t)mol] = (float)(sa / 32.0);
    } else if (ln == 63) {
      double sh = 0.0;
      for (int n = 0; n < 32; ++n) sh += sLP[ms][32 + n];
      out[2232320 + (size_t)mol] = (float)(sh / 32.0);
    }
  } else if (ln < 62) {
    const int e = ln;
    const int nu_ = (e < 31) ? e : (e - 30);
    const int nv_ = (e < 31) ? (e + 1) : (e - 31);
    double lex = 0.0;
    double lt[4] = {0.0, 0.0, 0.0, 0.0};
    for (int i = 0; i < 17; ++i) {
      const double f = (double)sNF[ms][nu_][i];
      lex = fma(f, (double)w_eex[i], lex);
      #pragma unroll
      for (int c = 0; c < 4; ++c) lt[c] = fma(f, (double)w_ety[i * 4 + c], lt[c]);
    }
    for (int i = 0; i < 17; ++i) {
      const double f = (double)sNF[ms][nv_][i];
      lex = fma(f, (double)w_eex[17 + i], lex);
      #pragma unroll
      for (int c = 0; c < 4; ++c) lt[c] = fma(f, (double)w_ety[(17 + i) * 4 + c], lt[c]);
    }
    lex += (double)b_eex[0];
    #pragma unroll
    for (int c = 0; c < 4; ++c) lt[c] += (double)b_ety[c];

    const double pex = 1.0 / (1.0 + exp(-lex));
    out[3252224 + (size_t)mol * 62 + e] = (pex > 0.5) ? 1.f : 0.f;

    const uint32_t tbase = ((uint32_t)mol * 62u + (uint32_t)e) * 4u;
    int tsel = 0; double tbest = 0.0;
    #pragma unroll
    for (int c = 0; c < 4; ++c) {
      const double g = (double)jgumbel(k3p.a, k3p.b, tbase + (uint32_t)c);
      const double sc = lt[c] + g;
      if (c == 0 || sc > tbest) { tbest = sc; tsel = c; }
    }
    const size_t o = 2236416 + ((size_t)mol * 62 + e) * 4;
    #pragma unroll
    for (int c = 0; c < 4; ++c) out[o + c] = (c == tsel) ? 1.f : 0.f;
  }
}

extern "C" void kernel_launch(void* const* d_in, const int* in_sizes, int n_in,
                              void* d_out, int out_size, void* d_ws, size_t ws_size,
                              hipStream_t stream) {
  (void)in_sizes; (void)n_in; (void)out_size; (void)d_ws; (void)ws_size;
  hipLaunchKernelGGL(gen_kernel, dim3(2048), dim3(256), 0, stream,
                     (const float*)d_in[0],  (const float*)d_in[1],
                     (const float*)d_in[2],  (const float*)d_in[3],
                     (const float*)d_in[4],  (const float*)d_in[5],
                     (const float*)d_in[6],  (const float*)d_in[7],
                     (const float*)d_in[8],  (const float*)d_in[9],
                     (const float*)d_in[10], (const float*)d_in[11],
                     (const float*)d_in[12], (const float*)d_in[13],
                     (const float*)d_in[14], (const float*)d_in[15],
                     (const float*)d_in[16], (const float*)d_in[17],
                     (const float*)d_in[18], (const float*)d_in[19],
                     (const float*)d_in[20], (float*)d_out);
}

// Round 11
// 383.979 us; speedup vs baseline: 1.4719x; 1.1259x over previous
//
#include <hip/hip_runtime.h>
#include <stdint.h>
#include <math.h>

// ---------------------------------------------------------------------------
// Generator_44555990728950. B=4096 molecules, N=32 nodes (chain), H=128,
// 16 GAT layers. Two node classes per molecule (edge {0,31}, interior
// {1..30}); deterministic pipeline fp64; JAX partitionable threefry
// bit-exact; outputs fp32.
// R11: W staged into LDS as f64 (exact f32->f64 cvt at staging time),
// double-buffered 32-row chunks. Compute k-loop = ds_read_b128 W +
// ds_read_b128 x(broadcast) + 4 v_fma_f64 -- no cvt, no 64-bit address
// arithmetic, compiler-batchable LDS latency. 8 molecules per 512-thread
// block (1 wave each), 1 block/CU (103 KB LDS), 512 blocks.
// Staging overlapped with compute; 64 barriers total, each pre-drained.
// ---------------------------------------------------------------------------

struct U2 { uint32_t a, b; };

// Threefry-2x32, 20 rounds, exactly as jax._src.prng
__device__ __forceinline__ U2 threefry(uint32_t k0, uint32_t k1, uint32_t x0, uint32_t x1) {
  const uint32_t ks2 = k0 ^ k1 ^ 0x1BD11BDAu;
#define TFR(r) { x0 += x1; x1 = (x1 << (r)) | (x1 >> (32 - (r))); x1 ^= x0; }
  x0 += k0;  x1 += k1;
  TFR(13) TFR(15) TFR(26) TFR(6)
  x0 += k1;  x1 += ks2 + 1u;
  TFR(17) TFR(29) TFR(16) TFR(24)
  x0 += ks2; x1 += k0 + 2u;
  TFR(13) TFR(15) TFR(26) TFR(6)
  x0 += k0;  x1 += k1 + 3u;
  TFR(17) TFR(29) TFR(16) TFR(24)
  x0 += k1;  x1 += ks2 + 4u;
  TFR(13) TFR(15) TFR(26) TFR(6)
  x0 += ks2; x1 += k0 + 5u;
#undef TFR
  U2 r; r.a = x0; r.b = x1; return r;
}

// partitionable random_bits, 32-bit: counter = flat index; fold o1^o2
__device__ __forceinline__ uint32_t pbits(uint32_t k0, uint32_t k1, uint32_t ctr) {
  U2 r = threefry(k0, k1, 0u, ctr);
  return r.a ^ r.b;
}

__device__ __forceinline__ float bits_to_unit(uint32_t bits) {
  return __uint_as_float((bits >> 9) | 0x3f800000u) - 1.0f;  // [0,1)
}

// f32 uniform(1e-6, 1-1e-6) -> gumbel, exactly jax's f32 path
__device__ __forceinline__ float jgumbel(uint32_t k0, uint32_t k1, uint32_t ctr) {
  const float minv = 1e-6f;
  const float maxv = (float)(1.0 - 1e-6);
  const float span = maxv - minv;
  float f = bits_to_unit(pbits(k0, k1, ctr));
  float u = fmaxf(minv, __fadd_rn(__fmul_rn(f, span), minv));
  return -logf(-logf(u));
}

#define NW 8   // waves (= molecules) per 512-thread block

extern "C" __global__ void __launch_bounds__(512, 1)
gen_kernel(const float* __restrict__ noise,
           const float* __restrict__ w1,
           const float* __restrict__ b1,
           const float* __restrict__ gat_w,
           const float* __restrict__ gat_b,
           const float* __restrict__ att_src,
           const float* __restrict__ att_dst,
           const float* __restrict__ w_atom,
           const float* __restrict__ b_atom,
           const float* __restrict__ w_hyb,
           const float* __restrict__ b_hyb,
           const float* __restrict__ w_deg,
           const float* __restrict__ b_deg,
           const float* __restrict__ w_chg,
           const float* __restrict__ b_chg,
           const float* __restrict__ w_arom,
           const float* __restrict__ b_arom,
           const float* __restrict__ w_eex,
           const float* __restrict__ b_eex,
           const float* __restrict__ w_ety,
           const float* __restrict__ b_ety,
           float* __restrict__ out)
{
  __shared__ __align__(16) double sW[2][32][128];   // 64 KB f64 W ping-pong
  __shared__ __align__(16) double sX[NW][128][2];   // 16 KB {xe,xi} per k
  __shared__ double sScr[NW][32];                    // head logits
  __shared__ float  sNF[NW][32][17];                 // node features
  __shared__ double sLP[NW][64];                     // lp scratch

  const int t  = threadIdx.x;                        // 0..511
  const int wv = t >> 6;                             // wave = molecule slot
  const int ln = t & 63;
  const int mol = blockIdx.x * NW + wv;
  const int c0 = ln << 1;                            // lane's two columns

  // ---- issue staging loads for chunk g=0 (layer 0, rows 0..31)
  float sr[8];
  #pragma unroll
  for (int j = 0; j < 8; ++j) sr[j] = gat_w[t + j * 512];

  // ---------------- phase 0: x0 = relu(noise @ w1 + b1)
  {
    const float2 nz = *(const float2*)(noise + (size_t)mol * 128 + c0);
    sX[wv][c0][0]     = (double)nz.x;  sX[wv][c0][1]     = (double)nz.x;
    sX[wv][c0 + 1][0] = (double)nz.y;  sX[wv][c0 + 1][1] = (double)nz.y;
    double h0 = 0.0, h1 = 0.0;
    #pragma unroll 8
    for (int k = 0; k < 128; ++k) {
      const double nx = sX[wv][k][0];
      const float2 w  = *(const float2*)(w1 + k * 128 + c0);
      h0 = fma(nx, (double)w.x, h0);
      h1 = fma(nx, (double)w.y, h1);
    }
    const float2 bb = *(const float2*)(b1 + c0);
    const double x0a = fmax(h0 + (double)bb.x, 0.0);
    const double x0b = fmax(h1 + (double)bb.y, 0.0);
    double2 wa = {x0a, x0a}, wb = {x0b, x0b};
    *(double2*)&sX[wv][c0][0]     = wa;
    *(double2*)&sX[wv][c0 + 1][0] = wb;
  }
  // ---- finish staging chunk 0 into buffer 0 (stride-512: 2-way banks, free)
  {
    double* dst = &sW[0][0][0];
    #pragma unroll
    for (int j = 0; j < 8; ++j) dst[t + j * 512] = (double)sr[j];
  }
  __syncthreads();

  // ---------------- 16 GAT layers; W from LDS f64, double-buffered chunks
  for (int l = 0; l < 16; ++l) {
    double aEx = 0.0, aEy = 0.0, aIx = 0.0, aIy = 0.0;
    #pragma unroll
    for (int c = 0; c < 4; ++c) {
      const int g = l * 4 + c;
      const bool more = (g < 63);
      if (more) {
        const int base = (g + 1) * 4096 + t;
        #pragma unroll
        for (int j = 0; j < 8; ++j) sr[j] = gat_w[base + j * 512];
      }
      // compute rows [c*32, c*32+32) from buffer g&1
      const double* __restrict__ Wb = &sW[g & 1][0][0];
      const double* __restrict__ Xb = &sX[wv][c * 32][0];
      #pragma unroll 8
      for (int kk = 0; kk < 32; ++kk) {
        const double2 X  = *(const double2*)(Xb + kk * 2);     // broadcast
        const double2 Wv = *(const double2*)(Wb + kk * 128 + c0);
        aEx = fma(X.x, Wv.x, aEx); aEy = fma(X.x, Wv.y, aEy);
        aIx = fma(X.y, Wv.x, aIx); aIy = fma(X.y, Wv.y, aIy);
      }
      if (more) {
        double* dst = &sW[(g + 1) & 1][0][0];
        #pragma unroll
        for (int j = 0; j < 8; ++j) dst[t + j * 512] = (double)sr[j];
      }
      __syncthreads();
    }

    // ---- epilogue: bias, attention, residual (wave-private)
    {
      const float2 bb = *(const float2*)(gat_b + l * 128 + c0);
      aEx += (double)bb.x; aEy += (double)bb.y;
      aIx += (double)bb.x; aIy += (double)bb.y;
    }
    const float2 av = *(const float2*)(att_src + l * 128 + c0);
    const float2 dv = *(const float2*)(att_dst + l * 128 + c0);
    const double ax = (double)av.x, ay = (double)av.y;
    const double dx = (double)dv.x, dy = (double)dv.y;
    double esE = fma(aEy, ay, aEx * ax), edE = fma(aEy, dy, aEx * dx);
    double esI = fma(aIy, ay, aIx * ax), edI = fma(aIy, dy, aIx * dx);
    #pragma unroll
    for (int o = 1; o < 64; o <<= 1) {
      esE += __shfl_xor(esE, o, 64); edE += __shfl_xor(edE, o, 64);
      esI += __shfl_xor(esI, o, 64); edI += __shfl_xor(edI, o, 64);
    }
    const double2 ra = *(const double2*)&sX[wv][c0][0];
    const double2 rb = *(const double2*)&sX[wv][c0 + 1][0];

    double s0 = edE + esE; s0 = (s0 >= 0.0) ? s0 : 0.2 * s0;
    double s1 = edE + esI; s1 = (s1 >= 0.0) ? s1 : 0.2 * s1;
    const double me  = fmax(s0, s1);
    const double p0  = exp(s0 - me), p1 = exp(s1 - me);
    const double den = p0 + p1;
    const double A0 = p0 / den, A1 = p1 / den;
    const double oEx = A0 * aEx + A1 * aIx;
    const double oEy = A0 * aEy + A1 * aIy;
    const double tIx = (1.0 / 3.0) * aIx, tIy = (1.0 / 3.0) * aIy;
    const double oIx = (tIx + tIx) + tIx;
    const double oIy = (tIy + tIy) + tIy;

    double2 na, nb;
    na.x = fmax(ra.x + oEx, 0.0);  na.y = fmax(ra.y + oIx, 0.0);
    nb.x = fmax(rb.x + oEy, 0.0);  nb.y = fmax(rb.y + oIy, 0.0);
    *(double2*)&sX[wv][c0][0]     = na;
    *(double2*)&sX[wv][c0 + 1][0] = nb;
  }

  // ---------------- phase A: head logits per class (lanes 0..15)
  if (ln < 16) {
    double ae = 0.0, aiv = 0.0;
    if (ln < 10) {
      for (int c = 0; c < 128; ++c) {
        const double2 X = *(const double2*)&sX[wv][c][0];
        const double wv_ = (double)w_atom[c * 10 + ln];
        ae  = fma(X.x, wv_, ae);
        aiv = fma(X.y, wv_, aiv);
      }
      const double ba = (double)b_atom[ln];
      sScr[wv][ln]      = ae + ba;
      sScr[wv][10 + ln] = aiv + ba;
    } else if (ln < 13) {
      const int j = ln - 10;
      for (int c = 0; c < 128; ++c) {
        const double2 X = *(const double2*)&sX[wv][c][0];
        const double wv_ = (double)w_hyb[c * 3 + j];
        ae  = fma(X.x, wv_, ae);
        aiv = fma(X.y, wv_, aiv);
      }
      const double bh = (double)b_hyb[j];
      sScr[wv][20 + j] = ae + bh;
      sScr[wv][23 + j] = aiv + bh;
    } else {
      const int which = ln - 13;             // 0=deg 1=chg 2=arom
      const float* wp = (which == 0) ? w_deg : (which == 1) ? w_chg : w_arom;
      for (int c = 0; c < 128; ++c) {
        const double2 X = *(const double2*)&sX[wv][c][0];
        const double wv_ = (double)wp[c];
        ae  = fma(X.x, wv_, ae);
        aiv = fma(X.y, wv_, aiv);
      }
      const double bz = (double)((which == 0) ? b_deg[0] : (which == 1) ? b_chg[0] : b_arom[0]);
      sScr[wv][26 + which] = ae + bz;
      sScr[wv][29 + which] = aiv + bz;
    }
  }

  // partitionable split(key(42),4): child_i = threefry((0,42),(0,i))
  const U2 k0p = threefry(0u, 42u, 0u, 0u);
  const U2 k1p = threefry(0u, 42u, 0u, 1u);
  const U2 k2p = threefry(0u, 42u, 0u, 2u);
  const U2 k3p = threefry(0u, 42u, 0u, 3u);

  // ---------------- phase B: per-node sampling (lanes 0..31)
  if (ln < 32) {
    const int n = ln;
    const int lb = (n == 0 || n == 31) ? 0 : 10;
    const int hb = (n == 0 || n == 31) ? 20 : 23;
    const int zb = (n == 0 || n == 31) ? 26 : 29;
    const double* scr = sScr[wv];

    double m = scr[lb];
    #pragma unroll
    for (int a = 1; a < 10; ++a) m = fmax(m, scr[lb + a]);
    double lsum = 0.0;
    #pragma unroll
    for (int a = 0; a < 10; ++a) lsum += exp(scr[lb + a] - m);
    const double lse = log(lsum);
    const uint32_t abase = ((uint32_t)mol * 32u + (uint32_t)n) * 10u;
    int asel = 0; double abest = 0.0;
    #pragma unroll
    for (int a = 0; a < 10; ++a) {
      const double g = (double)jgumbel(k0p.a, k0p.b, abase + (uint32_t)a);
      const double sc = scr[lb + a] + g;
      if (a == 0 || sc > abest) { abest = sc; asel = a; }
    }
    sLP[wv][n] = (scr[lb + asel] - m) - lse;

    double m2 = fmax(fmax(scr[hb], scr[hb + 1]), scr[hb + 2]);
    double ls2 = exp(scr[hb] - m2) + exp(scr[hb + 1] - m2) + exp(scr[hb + 2] - m2);
    const double lse2 = log(ls2);
    const uint32_t hbase = ((uint32_t)mol * 32u + (uint32_t)n) * 3u;
    int hsel = 0; double hbest = 0.0;
    #pragma unroll
    for (int j = 0; j < 3; ++j) {
      const double g = (double)jgumbel(k1p.a, k1p.b, hbase + (uint32_t)j);
      const double sc = scr[hb + j] + g;
      if (j == 0 || sc > hbest) { hbest = sc; hsel = j; }
    }
    sLP[wv][32 + n] = (scr[hb + hsel] - m2) - lse2;

    const double deg = 1.0 / (1.0 + exp(-scr[zb]));
    const double chg = tanh(scr[zb + 1]);
    const double pr  = 1.0 / (1.0 + exp(-scr[zb + 2]));
    const uint32_t ridx = (uint32_t)mol * 32u + (uint32_t)n;
    const double uu = (double)bits_to_unit(pbits(k2p.a, k2p.b, ridx));
    const double arom = (uu < pr) ? 1.0 : 0.0;
    const double valt[10] = {4.0/5.0, 3.0/5.0, 2.0/5.0, 1.0/5.0, 4.0/5.0,
                             2.0/5.0, 6.0/5.0, 1.0/5.0, 4.0/5.0, 4.0/5.0};
    double nf[17];
    #pragma unroll
    for (int i = 0; i < 10; ++i) nf[i] = (i == asel) ? 1.0 : 0.0;
    nf[10] = deg; nf[11] = chg;
    #pragma unroll
    for (int j = 0; j < 3; ++j) nf[12 + j] = (j == hsel) ? 1.0 : 0.0;
    nf[15] = arom; nf[16] = valt[asel];

    const size_t o = ((size_t)mol * 32 + n) * 17;
    #pragma unroll
    for (int i = 0; i < 17; ++i) {
      sNF[wv][n][i] = (float)nf[i];
      out[o + i] = (float)nf[i];
    }
  }

  // ---------------- phase C: lp means + edge heads (wave-private)
  if (ln == 62) {
    double sa = 0.0;
    for (int n = 0; n < 32; ++n) sa += sLP[wv][n];
    out[2228224 + (size_t)mol] = (float)(sa / 32.0);
  } else if (ln == 63) {
    double sh = 0.0;
    for (int n = 0; n < 32; ++n) sh += sLP[wv][32 + n];
    out[2232320 + (size_t)mol] = (float)(sh / 32.0);
  } else {
    const int e = ln;                       // 0..61
    const int nu_ = (e < 31) ? e : (e - 30);
    const int nv_ = (e < 31) ? (e + 1) : (e - 31);
    double lex = 0.0;
    double lt[4] = {0.0, 0.0, 0.0, 0.0};
    for (int i = 0; i < 17; ++i) {
      const double f = (double)sNF[wv][nu_][i];
      lex = fma(f, (double)w_eex[i], lex);
      #pragma unroll
      for (int c = 0; c < 4; ++c) lt[c] = fma(f, (double)w_ety[i * 4 + c], lt[c]);
    }
    for (int i = 0; i < 17; ++i) {
      const double f = (double)sNF[wv][nv_][i];
      lex = fma(f, (double)w_eex[17 + i], lex);
      #pragma unroll
      for (int c = 0; c < 4; ++c) lt[c] = fma(f, (double)w_ety[(17 + i) * 4 + c], lt[c]);
    }
    lex += (double)b_eex[0];
    #pragma unroll
    for (int c = 0; c < 4; ++c) lt[c] += (double)b_ety[c];

    const double pex = 1.0 / (1.0 + exp(-lex));
    out[3252224 + (size_t)mol * 62 + e] = (pex > 0.5) ? 1.f : 0.f;

    const uint32_t tbase = ((uint32_t)mol * 62u + (uint32_t)e) * 4u;
    int tsel = 0; double tbest = 0.0;
    #pragma unroll
    for (int c = 0; c < 4; ++c) {
      const double g = (double)jgumbel(k3p.a, k3p.b, tbase + (uint32_t)c);
      const double sc = lt[c] + g;
      if (c == 0 || sc > tbest) { tbest = sc; tsel = c; }
    }
    const size_t o = 2236416 + ((size_t)mol * 62 + e) * 4;
    #pragma unroll
    for (int c = 0; c < 4; ++c) out[o + c] = (c == tsel) ? 1.f : 0.f;
  }
}

extern "C" void kernel_launch(void* const* d_in, const int* in_sizes, int n_in,
                              void* d_out, int out_size, void* d_ws, size_t ws_size,
                              hipStream_t stream) {
  (void)in_sizes; (void)n_in; (void)out_size; (void)d_ws; (void)ws_size;
  hipLaunchKernelGGL(gen_kernel, dim3(512), dim3(512), 0, stream,
                     (const float*)d_in[0],  (const float*)d_in[1],
                     (const float*)d_in[2],  (const float*)d_in[3],
                     (const float*)d_in[4],  (const float*)d_in[5],
                     (const float*)d_in[6],  (const float*)d_in[7],
                     (const float*)d_in[8],  (const float*)d_in[9],
                     (const float*)d_in[10], (const float*)d_in[11],
                     (const float*)d_in[12], (const float*)d_in[13],
                     (const float*)d_in[14], (const float*)d_in[15],
                     (const float*)d_in[16], (const float*)d_in[17],
                     (const float*)d_in[18], (const float*)d_in[19],
                     (const float*)d_in[20], (float*)d_out);
}